// Round 4
// baseline (281.469 us; speedup 1.0000x reference)
//
#include <hip/hip_runtime.h>

// x: [B=2, C=3, D=128, H=160, W=160] fp32, num_steps=6
#define BB 2
#define DD 128
#define HH 160
#define WW 160
constexpr int S   = DD * HH * WW;   // voxels per batch   = 3,276,800
constexpr int PL  = HH * WW;        // plane (h*w)        = 25,600
constexpr int VPB = 512;            // voxels per block (2 per thread)
constexpr int BPP = PL / VPB;       // 50 blocks per plane
constexpr int NBLK = BB * DD * BPP; // 12800 blocks
constexpr int PER_XCD = NBLK / 8;   // contiguous 32-plane slab per XCD

struct I3 { int d, h, w; };

__device__ __forceinline__ I3 warp_coords(int d, int h, int w,
                                          float f0, float f1, float f2) {
    // round-half-to-even (jnp.round == rintf), clamp per-dim
    I3 r;
    r.d = (int)fminf(fmaxf(rintf((float)d + f0), 0.0f), (float)(DD - 1));
    r.h = (int)fminf(fmaxf(rintf((float)h + f1), 0.0f), (float)(HH - 1));
    r.w = (int)fminf(fmaxf(rintf((float)w + f2), 0.0f), (float)(WW - 1));
    return r;
}

template <bool SOA>
__device__ __forceinline__ void load3(const float* __restrict__ v, int b, int idx,
                                      float s, float& o0, float& o1, float& o2) {
    if constexpr (SOA) {
        int i = b * 3 * S + idx;
        o0 = v[i] * s; o1 = v[i + S] * s; o2 = v[i + 2 * S] * s;
    } else {
        int i = (b * S + idx) * 3;
        o0 = v[i] * s; o1 = v[i + 1] * s; o2 = v[i + 2] * s;
    }
}

// Two fused squaring steps for one voxel:
//   v1(p) = f(p) + f(q(p));  out = v1(p) + v1(r),  r = round(p + v1(p))
// where f = scale * vin. FP grouping matches the unfused two-pass sequence exactly.
template <bool IN_SOA>
__device__ __forceinline__ void fused2(const float* __restrict__ vin, int b,
                                       int d, int h, int w, float scale,
                                       float& o0, float& o1, float& o2) {
    int p = (d * HH + h) * WW + w;
    float f0, f1, f2;
    load3<IN_SOA>(vin, b, p, scale, f0, f1, f2);
    I3 q = warp_coords(d, h, w, f0, f1, f2);
    float g0, g1, g2;
    load3<IN_SOA>(vin, b, (q.d * HH + q.h) * WW + q.w, scale, g0, g1, g2);
    float v10 = f0 + g0, v11 = f1 + g1, v12 = f2 + g2;          // v1(p)
    I3 r = warp_coords(d, h, w, v10, v11, v12);
    float fr0, fr1, fr2;
    load3<IN_SOA>(vin, b, (r.d * HH + r.h) * WW + r.w, scale, fr0, fr1, fr2);
    I3 qr = warp_coords(r.d, r.h, r.w, fr0, fr1, fr2);
    float gr0, gr1, gr2;
    load3<IN_SOA>(vin, b, (qr.d * HH + qr.h) * WW + qr.w, scale, gr0, gr1, gr2);
    float v1r0 = fr0 + gr0, v1r1 = fr1 + gr1, v1r2 = fr2 + gr2; // v1(r)
    o0 = v10 + v1r0; o1 = v11 + v1r1; o2 = v12 + v1r2;
}

template <bool IN_SOA, bool OUT_SOA>
__global__ __launch_bounds__(256) void step2_k(const float* __restrict__ vin,
                                               float* __restrict__ vout,
                                               float scale) {
    // XCD-aware swizzle: each XCD owns a contiguous 32-plane slab.
    int bid = blockIdx.x;
    int nb  = (bid >> 3) + (bid & 7) * PER_XCD;
    int b   = nb / (DD * BPP);
    int rr  = nb - b * (DD * BPP);
    int d   = rr / BPP;
    int ip0 = (rr - d * BPP) * VPB + threadIdx.x;
    int ip1 = ip0 + 256;
    int w0 = ip0 % WW, h0 = ip0 / WW;
    int w1 = ip1 % WW, h1 = ip1 / WW;

    float a0, a1, a2, c0, c1, c2;
    fused2<IN_SOA>(vin, b, d, h0, w0, scale, a0, a1, a2);
    fused2<IN_SOA>(vin, b, d, h1, w1, scale, c0, c1, c2);

    int p0 = d * PL + ip0, p1 = d * PL + ip1;
    if constexpr (OUT_SOA) {
        int s0 = b * 3 * S + p0, s1 = b * 3 * S + p1;
        vout[s0] = a0; vout[s0 + S] = a1; vout[s0 + 2 * S] = a2;
        vout[s1] = c0; vout[s1 + S] = c1; vout[s1 + 2 * S] = c2;
    } else {
        int i0 = (b * S + p0) * 3, i1 = (b * S + p1) * 3;
        vout[i0] = a0; vout[i0 + 1] = a1; vout[i0 + 2] = a2;
        vout[i1] = c0; vout[i1 + 1] = c1; vout[i1 + 2] = c2;
    }
}

// ---- fallback: single-step kernel (round-3 version), used only if ws is small ----
template <bool IN_SOA, bool OUT_SOA>
__global__ __launch_bounds__(256) void step_k(const float* __restrict__ vin,
                                              float* __restrict__ vout,
                                              float scale) {
    int bid = blockIdx.x;
    int nb  = (bid >> 3) + (bid & 7) * PER_XCD;
    int b   = nb / (DD * BPP);
    int rr  = nb - b * (DD * BPP);
    int d   = rr / BPP;
    int ip0 = (rr - d * BPP) * VPB + threadIdx.x;
    for (int v = 0; v < 2; ++v) {
        int ip = ip0 + v * 256;
        int w = ip % WW, h = ip / WW;
        int p = d * PL + ip;
        float f0, f1, f2;
        load3<IN_SOA>(vin, b, p, scale, f0, f1, f2);
        I3 q = warp_coords(d, h, w, f0, f1, f2);
        float g0, g1, g2;
        load3<IN_SOA>(vin, b, (q.d * HH + q.h) * WW + q.w, scale, g0, g1, g2);
        if constexpr (OUT_SOA) {
            int s0 = b * 3 * S + p;
            vout[s0] = f0 + g0; vout[s0 + S] = f1 + g1; vout[s0 + 2 * S] = f2 + g2;
        } else {
            int i0 = (b * S + p) * 3;
            vout[i0] = f0 + g0; vout[i0 + 1] = f1 + g1; vout[i0 + 2] = f2 + g2;
        }
    }
}

extern "C" void kernel_launch(void* const* d_in, const int* in_sizes, int n_in,
                              void* d_out, int out_size, void* d_ws, size_t ws_size,
                              hipStream_t stream) {
    const float* x = (const float*)d_in[0];
    float* out = (float*)d_out;
    float* ws  = (float*)d_ws;

    const size_t fieldf = (size_t)BB * S * 3;            // floats per tight AoS field
    const size_t need   = 2 * fieldf * sizeof(float);    // 157,286,400 bytes

    if (ws_size >= need) {
        // 3 fused kernels: steps (1,2), (3,4), (5,6). Scale fused into kernel 1.
        float* A = ws;
        float* B = ws + fieldf;
        step2_k<true,  false><<<NBLK, 256, 0, stream>>>(x, A, 1.0f / 64.0f);
        step2_k<false, false><<<NBLK, 256, 0, stream>>>(A, B, 1.0f);
        step2_k<false, true ><<<NBLK, 256, 0, stream>>>(B, out, 1.0f);
    } else {
        // 6 unfused passes, ping-pong ws <-> out.
        step_k<true,  false><<<NBLK, 256, 0, stream>>>(x,   ws,  1.0f / 64.0f);
        step_k<false, false><<<NBLK, 256, 0, stream>>>(ws,  out, 1.0f);
        step_k<false, false><<<NBLK, 256, 0, stream>>>(out, ws,  1.0f);
        step_k<false, false><<<NBLK, 256, 0, stream>>>(ws,  out, 1.0f);
        step_k<false, false><<<NBLK, 256, 0, stream>>>(out, ws,  1.0f);
        step_k<false, true ><<<NBLK, 256, 0, stream>>>(ws,  out, 1.0f);
    }
}